// Round 1
// baseline (772.914 us; speedup 1.0000x reference)
//
#include <hip/hip_runtime.h>
#include <math.h>

#define NTOT 262144   // total nodes
#define BG   64       // graphs
#define NNPG 4096     // nodes per graph
#define ET   1048576  // directed edges
#define HD   128
#define LD   64
#define NSEG 129

// ---------------- CSR build ----------------
__global__ void k_count(const int* __restrict__ ei, int* __restrict__ cnt){
  int e = blockIdx.x*256 + threadIdx.x;
  atomicAdd(&cnt[ei[ET + e]], 1);
}

__global__ void k_dinv(const int* __restrict__ cnt, float* __restrict__ dinv){
  int i = blockIdx.x*256 + threadIdx.x;
  dinv[i] = rsqrtf((float)cnt[i] + 1.0f);   // +1 self-loop
}

__global__ void k_scan1(const int* __restrict__ cnt, int* __restrict__ off, int* __restrict__ bsum){
  __shared__ int sh[256];
  int tid = threadIdx.x;
  int i = blockIdx.x*256 + tid;
  int v = cnt[i]; sh[tid] = v; __syncthreads();
  for (int d = 1; d < 256; d <<= 1){
    int t = (tid >= d) ? sh[tid-d] : 0; __syncthreads();
    sh[tid] += t; __syncthreads();
  }
  off[i] = sh[tid] - v;                 // exclusive within block
  if (tid == 255) bsum[blockIdx.x] = sh[255];
}

__global__ void k_scan2(int* __restrict__ bsum){
  __shared__ int sh[1024];
  int tid = threadIdx.x;
  int v = bsum[tid]; sh[tid] = v; __syncthreads();
  for (int d = 1; d < 1024; d <<= 1){
    int t = (tid >= d) ? sh[tid-d] : 0; __syncthreads();
    sh[tid] += t; __syncthreads();
  }
  bsum[tid] = sh[tid] - v;              // exclusive
}

__global__ void k_scan3(int* __restrict__ off, const int* __restrict__ bsum, int* __restrict__ cursor){
  int i = blockIdx.x*256 + threadIdx.x;
  int o = off[i] + bsum[blockIdx.x];
  off[i] = o; cursor[i] = o;
}

__global__ void k_place(const int* __restrict__ ei, int* __restrict__ cursor, int* __restrict__ csrc){
  int e = blockIdx.x*256 + threadIdx.x;
  int r = ei[e], c = ei[ET + e];
  int p = atomicAdd(&cursor[c], 1);
  csrc[p] = r;
}

// ---------------- encoder piecewise-linear tables ----------------
// breakpoints/kinds/ranks for relu(a*w1[j]+b1[j]); kind 0: w>0 (active a>t),
// kind 1: w<0 (active a<t), kind 2: w==0 (active iff b>0, t=+inf never counted)
__global__ void k_tab1a(const float* __restrict__ w1, const float* __restrict__ b1,
                        float* __restrict__ t1, int* __restrict__ kind1, int* __restrict__ rank1){
  __shared__ float ts[128]; __shared__ int ks[128];
  int j = threadIdx.x;
  float w = w1[j], b = b1[j];
  float t; int kind;
  if (w != 0.0f){ t = -b / w; kind = (w > 0.0f) ? 0 : 1; }
  else          { t = INFINITY; kind = 2; }
  ts[j] = t; ks[j] = kind; __syncthreads();
  int r = 0;
  for (int q = 0; q < 128; q++){
    if (ks[q] != 2){
      float tq = ts[q];
      if (tq < t || (tq == t && q < j)) r++;
    }
  }
  t1[j] = t; kind1[j] = kind; rank1[j] = r;
}

__global__ void k_tab1b(const float* __restrict__ w1, const float* __restrict__ b1,
                        const float* __restrict__ w2, const int* __restrict__ kind1,
                        const int* __restrict__ rank1, float* __restrict__ A1, float* __restrict__ C1){
  int s = blockIdx.x, k = threadIdx.x;
  __shared__ float ws[128], bs[128]; __shared__ int kk[128], rr[128];
  ws[k] = w1[k]; bs[k] = b1[k]; kk[k] = kind1[k]; rr[k] = rank1[k]; __syncthreads();
  float a = 0.f, c = 0.f;
  for (int j = 0; j < 128; j++){
    int kd = kk[j];
    bool act = (kd == 0) ? (rr[j] < s) : (kd == 1) ? (rr[j] >= s) : (bs[j] > 0.0f);
    if (act){
      float v = w2[j*HD + k];
      a = fmaf(ws[j], v, a);
      c = fmaf(bs[j], v, c);
    }
  }
  A1[s*HD + k] = a; C1[s*HD + k] = c;
}

// ---------------- per-node scalars: ax = A(x), srow = A(1), seg1 ----------------
__global__ void k_ax(const float* __restrict__ x, const float* __restrict__ dinv,
                     const int* __restrict__ off, const int* __restrict__ cnt,
                     const int* __restrict__ csrc, const float* __restrict__ t1,
                     float* __restrict__ ax, float* __restrict__ srow, int* __restrict__ seg1){
  __shared__ float ts[128];
  if (threadIdx.x < 128) ts[threadIdx.x] = t1[threadIdx.x];
  __syncthreads();
  int i = blockIdx.x*256 + threadIdx.x;
  float di = dinv[i];
  float sx = di * x[i], s1 = di;       // self-loop terms
  int o = off[i], n = cnt[i];
  for (int t = 0; t < n; t++){
    int s = csrc[o + t];
    float ds = dinv[s];
    sx += ds * x[s];
    s1 += ds;
  }
  float a = di * sx;
  ax[i] = a; srow[i] = di * s1;
  int sc = 0;
  for (int q = 0; q < 128; q++) sc += (ts[q] < a) ? 1 : 0;
  seg1[i] = sc;
}

// ---------------- fused encoder GCN2 + relu + mean-pool ----------------
__global__ void __launch_bounds__(256) k_enc_agg(
    const float* __restrict__ dinv, const float* __restrict__ ax, const int* __restrict__ seg,
    const int* __restrict__ off, const int* __restrict__ cnt, const int* __restrict__ csrc,
    const float* __restrict__ A1, const float* __restrict__ C1,
    const float* __restrict__ b2, float* __restrict__ hgsum)
{
  int bid = blockIdx.x;                       // 512 blocks; graph->XCD-local swizzle
  int g    = (bid & 7) + ((bid >> 6) << 3);
  int part = (bid >> 3) & 7;
  int lane = threadIdx.x & 31;
  int nrow = threadIdx.x >> 5;                // 8 node-rows per block iter
  int base = g*NNPG + part*512;
  const float4* A1v = (const float4*)A1;
  const float4* C1v = (const float4*)C1;
  float4 bb = ((const float4*)b2)[lane];
  float gx = 0.f, gy = 0.f, gz = 0.f, gw = 0.f;
  for (int it = 0; it < 64; ++it){
    int i = base + it*8 + nrow;
    float di = dinv[i], a = ax[i];
    int s = seg[i];
    float d2 = di*di;
    float4 av = A1v[s*32 + lane];
    float4 cv = C1v[s*32 + lane];
    float ca = a*d2;
    float accx = ca*av.x + d2*cv.x;
    float accy = ca*av.y + d2*cv.y;
    float accz = ca*av.z + d2*cv.z;
    float accw = ca*av.w + d2*cv.w;
    int eo = off[i], n = cnt[i];
    for (int t = 0; t < n; t++){
      int src = csrc[eo + t];
      float wgt = dinv[src]*di;
      float wa  = wgt*ax[src];
      int ss = seg[src];
      float4 av2 = A1v[ss*32 + lane];
      float4 cv2 = C1v[ss*32 + lane];
      accx = fmaf(wa, av2.x, fmaf(wgt, cv2.x, accx));
      accy = fmaf(wa, av2.y, fmaf(wgt, cv2.y, accy));
      accz = fmaf(wa, av2.z, fmaf(wgt, cv2.z, accz));
      accw = fmaf(wa, av2.w, fmaf(wgt, cv2.w, accw));
    }
    gx += fmaxf(accx + bb.x, 0.f);
    gy += fmaxf(accy + bb.y, 0.f);
    gz += fmaxf(accz + bb.z, 0.f);
    gw += fmaxf(accw + bb.w, 0.f);
  }
  __shared__ float red[256*4];
  red[threadIdx.x*4+0] = gx; red[threadIdx.x*4+1] = gy;
  red[threadIdx.x*4+2] = gz; red[threadIdx.x*4+3] = gw;
  __syncthreads();
  if (nrow == 0){
    float tx=0.f, ty=0.f, tz=0.f, tw=0.f;
    for (int r2 = 0; r2 < 8; r2++){
      int t2 = (r2*32 + lane)*4;
      tx += red[t2]; ty += red[t2+1]; tz += red[t2+2]; tw += red[t2+3];
    }
    atomicAdd(&hgsum[g*HD + lane*4 + 0], tx);
    atomicAdd(&hgsum[g*HD + lane*4 + 1], ty);
    atomicAdd(&hgsum[g*HD + lane*4 + 2], tz);
    atomicAdd(&hgsum[g*HD + lane*4 + 3], tw);
  }
}

// ---------------- tiny dense chain: hg -> mu/lv/z -> zn -> u ----------------
__global__ void k_small(float* __restrict__ hg /* in: hgsum, scaled in place */,
                        const float* __restrict__ mu_w, const float* __restrict__ mu_b,
                        const float* __restrict__ lv_w, const float* __restrict__ lv_b,
                        const float* __restrict__ eps,
                        const float* __restrict__ zn_w, const float* __restrict__ zn_b,
                        const float* __restrict__ dec_w1,
                        float* __restrict__ zn, float* __restrict__ u,
                        float* __restrict__ out_mu, float* __restrict__ out_lv, float* __restrict__ out_z){
  int tid = threadIdx.x;
  for (int idx = tid; idx < BG*HD; idx += 256) hg[idx] *= (1.0f/4096.0f);
  __syncthreads();
  for (int o = tid; o < BG*LD; o += 256){
    int g = o >> 6, l = o & 63;
    const float* hgr = hg + g*HD;
    float m = mu_b[l], v = lv_b[l];
    for (int k = 0; k < HD; k++){
      float hv = hgr[k];
      m = fmaf(hv, mu_w[k*LD + l], m);
      v = fmaf(hv, lv_w[k*LD + l], v);
    }
    out_mu[o] = m; out_lv[o] = v;
    out_z[o]  = fmaf(expf(0.5f*v), eps[o], m);
  }
  __syncthreads();
  for (int o = tid; o < BG*HD; o += 256){
    int g = o >> 7, k = o & 127;
    float acc = zn_b[k];
    const float* zr = out_z + g*LD;
    for (int l = 0; l < LD; l++) acc = fmaf(zr[l], zn_w[l*HD + k], acc);
    zn[o] = acc;
  }
  __syncthreads();
  for (int o = tid; o < BG*HD; o += 256){
    int g = o >> 7, k = o & 127;
    float acc = 0.f;
    const float* zr = zn + g*HD;
    for (int j = 0; j < HD; j++) acc = fmaf(zr[j], dec_w1[j*HD + k], acc);
    u[o] = acc;
  }
}

// ---------------- decoder per-graph tables ----------------
__global__ void k_tab2a(const float* __restrict__ u, const float* __restrict__ b1,
                        float* __restrict__ t2, int* __restrict__ kind2, int* __restrict__ rank2){
  __shared__ float ts[128]; __shared__ int ks[128];
  int g = blockIdx.x, j = threadIdx.x;
  float w = u[g*HD + j], b = b1[j];
  float t; int kind;
  if (w != 0.0f){ t = -b / w; kind = (w > 0.0f) ? 0 : 1; }
  else          { t = INFINITY; kind = 2; }
  ts[j] = t; ks[j] = kind; __syncthreads();
  int r = 0;
  for (int q = 0; q < 128; q++){
    if (ks[q] != 2){
      float tq = ts[q];
      if (tq < t || (tq == t && q < j)) r++;
    }
  }
  t2[g*HD + j] = t; kind2[g*HD + j] = kind; rank2[g*HD + j] = r;
}

__global__ void k_tab2b(const float* __restrict__ u, const float* __restrict__ b1,
                        const float* __restrict__ w2, const int* __restrict__ kind2,
                        const int* __restrict__ rank2, float* __restrict__ A2, float* __restrict__ C2){
  int g = blockIdx.x / NSEG, s = blockIdx.x % NSEG;
  int k = threadIdx.x;
  __shared__ float ws[128], bs[128]; __shared__ int kk[128], rr[128];
  ws[k] = u[g*HD + k]; bs[k] = b1[k];
  kk[k] = kind2[g*HD + k]; rr[k] = rank2[g*HD + k];
  __syncthreads();
  float a = 0.f, c = 0.f;
  for (int j = 0; j < 128; j++){
    int kd = kk[j];
    bool act = (kd == 0) ? (rr[j] < s) : (kd == 1) ? (rr[j] >= s) : (bs[j] > 0.0f);
    if (act){
      float v = w2[j*HD + k];
      a = fmaf(ws[j], v, a);
      c = fmaf(bs[j], v, c);
    }
  }
  size_t o = ((size_t)g*NSEG + s)*HD + k;
  A2[o] = a; C2[o] = c;
}

__global__ void k_seg2(const float* __restrict__ t2, const float* __restrict__ srow, int* __restrict__ seg){
  __shared__ float ts[128];
  int b = blockIdx.x, g = b >> 3;
  if (threadIdx.x < 128) ts[threadIdx.x] = t2[g*HD + threadIdx.x];
  __syncthreads();
  int base = b*512;
  for (int i = base + threadIdx.x; i < base + 512; i += 256){
    float a = srow[i];
    int sc = 0;
    for (int q = 0; q < 128; q++) sc += (ts[q] < a) ? 1 : 0;
    seg[i] = sc;
  }
}

// ---------------- fused decoder GCN2 + relu + out-proj + tanh ----------------
__global__ void __launch_bounds__(256) k_dec_agg(
    const float* __restrict__ dinv, const float* __restrict__ srow, const int* __restrict__ seg,
    const int* __restrict__ off, const int* __restrict__ cnt, const int* __restrict__ csrc,
    const float* __restrict__ A2, const float* __restrict__ C2,
    const float* __restrict__ b2, const float* __restrict__ ow, const float* __restrict__ ob,
    float* __restrict__ recon)
{
  int bid = blockIdx.x;
  int g    = (bid & 7) + ((bid >> 6) << 3);
  int part = (bid >> 3) & 7;
  int lane = threadIdx.x & 31;
  int nrow = threadIdx.x >> 5;
  int base = g*NNPG + part*512;
  const float4* Av = (const float4*)(A2 + (size_t)g*NSEG*HD);
  const float4* Cv = (const float4*)(C2 + (size_t)g*NSEG*HD);
  float4 bb  = ((const float4*)b2)[lane];
  float4 owv = ((const float4*)ow)[lane];
  float obv = ob[0];
  for (int it = 0; it < 64; ++it){
    int i = base + it*8 + nrow;
    float di = dinv[i], a = srow[i];
    int s = seg[i];
    float d2 = di*di;
    float4 av = Av[s*32 + lane];
    float4 cv = Cv[s*32 + lane];
    float ca = a*d2;
    float accx = ca*av.x + d2*cv.x;
    float accy = ca*av.y + d2*cv.y;
    float accz = ca*av.z + d2*cv.z;
    float accw = ca*av.w + d2*cv.w;
    int eo = off[i], n = cnt[i];
    for (int t = 0; t < n; t++){
      int src = csrc[eo + t];
      float wgt = dinv[src]*di;
      float wa  = wgt*srow[src];
      int ss = seg[src];
      float4 av2 = Av[ss*32 + lane];
      float4 cv2 = Cv[ss*32 + lane];
      accx = fmaf(wa, av2.x, fmaf(wgt, cv2.x, accx));
      accy = fmaf(wa, av2.y, fmaf(wgt, cv2.y, accy));
      accz = fmaf(wa, av2.z, fmaf(wgt, cv2.z, accz));
      accw = fmaf(wa, av2.w, fmaf(wgt, cv2.w, accw));
    }
    float hx = fmaxf(accx + bb.x, 0.f);
    float hy = fmaxf(accy + bb.y, 0.f);
    float hz = fmaxf(accz + bb.z, 0.f);
    float hw = fmaxf(accw + bb.w, 0.f);
    float dsum = hx*owv.x + hy*owv.y + hz*owv.z + hw*owv.w;
    for (int o2 = 16; o2 > 0; o2 >>= 1) dsum += __shfl_down(dsum, o2, 32);
    if (lane == 0) recon[i] = tanhf(dsum + obv);
  }
}

// ---------------- launch ----------------
extern "C" void kernel_launch(void* const* d_in, const int* in_sizes, int n_in,
                              void* d_out, int out_size, void* d_ws, size_t ws_size,
                              hipStream_t stream){
  (void)in_sizes; (void)n_in; (void)out_size; (void)ws_size;
  const float* x      = (const float*)d_in[0];
  const float* eps    = (const float*)d_in[1];
  const float* enc_w1 = (const float*)d_in[2];
  const float* enc_b1 = (const float*)d_in[3];
  const float* enc_w2 = (const float*)d_in[4];
  const float* enc_b2 = (const float*)d_in[5];
  const float* mu_w   = (const float*)d_in[6];
  const float* mu_b   = (const float*)d_in[7];
  const float* lv_w   = (const float*)d_in[8];
  const float* lv_b   = (const float*)d_in[9];
  const float* zn_w   = (const float*)d_in[10];
  const float* zn_b   = (const float*)d_in[11];
  const float* dec_w1 = (const float*)d_in[12];
  const float* dec_b1 = (const float*)d_in[13];
  const float* dec_w2 = (const float*)d_in[14];
  const float* dec_b2 = (const float*)d_in[15];
  const float* out_w  = (const float*)d_in[16];
  const float* out_b  = (const float*)d_in[17];
  const int*   ei     = (const int*)d_in[18];

  float* out       = (float*)d_out;
  float* out_recon = out;
  float* out_mu    = out + NTOT;
  float* out_lv    = out_mu + BG*LD;
  float* out_z     = out_lv + BG*LD;

  char* w = (char*)d_ws;
  size_t off_b = 0;
  auto alloc = [&](size_t bytes)->void*{
    void* p = w + off_b;
    off_b += (bytes + 255) & ~(size_t)255;
    return p;
  };
  int*   cnt    = (int*)  alloc((size_t)NTOT*4);
  int*   csroff = (int*)  alloc((size_t)NTOT*4);
  int*   cursor = (int*)  alloc((size_t)NTOT*4);
  int*   csrc   = (int*)  alloc((size_t)ET*4);
  int*   seg1   = (int*)  alloc((size_t)NTOT*4);
  int*   seg2   = (int*)  alloc((size_t)NTOT*4);
  int*   bsum   = (int*)  alloc(1024*4);
  float* dinv   = (float*)alloc((size_t)NTOT*4);
  float* ax     = (float*)alloc((size_t)NTOT*4);
  float* srow   = (float*)alloc((size_t)NTOT*4);
  float* t1     = (float*)alloc(128*4);
  int*   kind1  = (int*)  alloc(128*4);
  int*   rank1  = (int*)  alloc(128*4);
  float* A1     = (float*)alloc((size_t)NSEG*HD*4);
  float* C1     = (float*)alloc((size_t)NSEG*HD*4);
  float* hgsum  = (float*)alloc((size_t)BG*HD*4);
  float* zn     = (float*)alloc((size_t)BG*HD*4);
  float* u      = (float*)alloc((size_t)BG*HD*4);
  float* t2     = (float*)alloc((size_t)BG*HD*4);
  int*   kind2  = (int*)  alloc((size_t)BG*HD*4);
  int*   rank2  = (int*)  alloc((size_t)BG*HD*4);
  float* A2     = (float*)alloc((size_t)BG*NSEG*HD*4);
  float* C2     = (float*)alloc((size_t)BG*NSEG*HD*4);

  hipMemsetAsync(cnt,   0, (size_t)NTOT*4, stream);
  hipMemsetAsync(hgsum, 0, (size_t)BG*HD*4, stream);

  k_count<<<ET/256, 256, 0, stream>>>(ei, cnt);
  k_dinv <<<NTOT/256, 256, 0, stream>>>(cnt, dinv);
  k_scan1<<<NTOT/256, 256, 0, stream>>>(cnt, csroff, bsum);
  k_scan2<<<1, 1024, 0, stream>>>(bsum);
  k_scan3<<<NTOT/256, 256, 0, stream>>>(csroff, bsum, cursor);
  k_place<<<ET/256, 256, 0, stream>>>(ei, cursor, csrc);

  k_tab1a<<<1, 128, 0, stream>>>(enc_w1, enc_b1, t1, kind1, rank1);
  k_ax   <<<NTOT/256, 256, 0, stream>>>(x, dinv, csroff, cnt, csrc, t1, ax, srow, seg1);
  k_tab1b<<<NSEG, 128, 0, stream>>>(enc_w1, enc_b1, enc_w2, kind1, rank1, A1, C1);

  k_enc_agg<<<512, 256, 0, stream>>>(dinv, ax, seg1, csroff, cnt, csrc, A1, C1, enc_b2, hgsum);

  k_small<<<1, 256, 0, stream>>>(hgsum, mu_w, mu_b, lv_w, lv_b, eps, zn_w, zn_b, dec_w1,
                                 zn, u, out_mu, out_lv, out_z);

  k_tab2a<<<BG, 128, 0, stream>>>(u, dec_b1, t2, kind2, rank2);
  k_tab2b<<<BG*NSEG, 128, 0, stream>>>(u, dec_b1, dec_w2, kind2, rank2, A2, C2);
  k_seg2 <<<512, 256, 0, stream>>>(t2, srow, seg2);

  k_dec_agg<<<512, 256, 0, stream>>>(dinv, srow, seg2, csroff, cnt, csrc, A2, C2,
                                     dec_b2, out_w, out_b, out_recon);
}

// Round 2
// 458.132 us; speedup vs baseline: 1.6871x; 1.6871x over previous
//
#include <hip/hip_runtime.h>
#include <math.h>

#define NTOT 262144   // total nodes
#define BG   64       // graphs
#define NNPG 4096     // nodes per graph
#define ET   1048576  // directed edges
#define HD   128
#define LD   64
#define NSEG 129

// ---------------- CSR build ----------------
__global__ void k_count(const int* __restrict__ ei, int* __restrict__ cnt){
  int e = blockIdx.x*256 + threadIdx.x;
  atomicAdd(&cnt[ei[ET + e]], 1);
}

// block-local exclusive scan of cnt + dinv
__global__ void k_scan1(const int* __restrict__ cnt, int* __restrict__ off,
                        int* __restrict__ bsum, float* __restrict__ dinv){
  __shared__ int sh[256];
  int tid = threadIdx.x;
  int i = blockIdx.x*256 + tid;
  int v = cnt[i]; sh[tid] = v;
  dinv[i] = rsqrtf((float)v + 1.0f);   // +1 self-loop
  __syncthreads();
  for (int d = 1; d < 256; d <<= 1){
    int t = (tid >= d) ? sh[tid-d] : 0; __syncthreads();
    sh[tid] += t; __syncthreads();
  }
  off[i] = sh[tid] - v;                 // exclusive within block
  if (tid == 255) bsum[blockIdx.x] = sh[255];
}

__global__ void k_scan2(int* __restrict__ bsum){
  __shared__ int sh[1024];
  int tid = threadIdx.x;
  int v = bsum[tid]; sh[tid] = v; __syncthreads();
  for (int d = 1; d < 1024; d <<= 1){
    int t = (tid >= d) ? sh[tid-d] : 0; __syncthreads();
    sh[tid] += t; __syncthreads();
  }
  bsum[tid] = sh[tid] - v;              // exclusive
}

__global__ void k_scan3(int* __restrict__ off, const int* __restrict__ bsum, int* __restrict__ cursor){
  int i = blockIdx.x*256 + threadIdx.x;
  int o = off[i] + bsum[blockIdx.x];
  off[i] = o; cursor[i] = o;
}

__global__ void k_place(const int* __restrict__ ei, int* __restrict__ cursor, int* __restrict__ csrc){
  int e = blockIdx.x*256 + threadIdx.x;
  int r = ei[e], c = ei[ET + e];
  int p = atomicAdd(&cursor[c], 1);
  csrc[p] = r;
}

// ---------------- encoder table: breakpoints + incremental segment build ----
// relu(a*w1[j]+b1[j]): kind 0: w>0 (active a>t), kind 1: w<0 (active a<t),
// kind 2: w==0 (active iff b>0). Segment s -> s+1 flips exactly the unit with
// rank s (ranks of breakpoints are unique), so table = base + 128 increments.
// AC layout (interleaved): float idx = s*256 + (k>>2)*8 + (k&3) for A, +4 for C
// -> per (s,lane) one contiguous 32B {A-float4, C-float4} pair.
__global__ void k_tab1(const float* __restrict__ w1, const float* __restrict__ b1,
                       const float* __restrict__ w2,
                       float* __restrict__ t1, float* __restrict__ AC1){
  __shared__ float ts[128], ws[128], bs[128];
  __shared__ int ks[128], jr[128];
  int j = threadIdx.x;
  float w = w1[j], b = b1[j];
  float t; int kind;
  if (w != 0.0f){ t = -b / w; kind = (w > 0.0f) ? 0 : 1; }
  else          { t = INFINITY; kind = 2; }
  ts[j] = t; ks[j] = kind; ws[j] = w; bs[j] = b; jr[j] = -1;
  __syncthreads();
  int r = 0;
  for (int q = 0; q < 128; q++){
    if (ks[q] != 2){
      float tq = ts[q];
      if (tq < t || (tq == t && q < j)) r++;
    }
  }
  t1[j] = t;
  if (kind != 2) jr[r] = j;
  __syncthreads();
  int k = j;
  float a = 0.f, c = 0.f;
  for (int q = 0; q < 128; q++){      // segment 0: kind1 all active
    int kd = ks[q];
    bool act = (kd == 1) || (kd == 2 && bs[q] > 0.0f);
    if (act){ float v = w2[q*HD + k]; a = fmaf(ws[q], v, a); c = fmaf(bs[q], v, c); }
  }
  int base = (k>>2)*8 + (k&3);
  AC1[base] = a; AC1[base+4] = c;
  for (int s = 0; s < 128; s++){
    int q = jr[s];
    if (q >= 0){
      float sg = (ks[q] == 0) ? 1.f : -1.f;
      float v  = w2[q*HD + k];
      a = fmaf(sg*ws[q], v, a);
      c = fmaf(sg*bs[q], v, c);
    }
    int o = (s+1)*256 + base;
    AC1[o] = a; AC1[o+4] = c;
  }
}

// ---------------- per-node scalars: ax=A(x), srow=A(1), seg1; packed records -
__global__ void k_ax(const float* __restrict__ x, const float* __restrict__ dinv,
                     const int* __restrict__ off, const int* __restrict__ cnt,
                     const int* __restrict__ csrc, const float* __restrict__ t1,
                     float4* __restrict__ recE, float4* __restrict__ recD){
  __shared__ float ts[128];
  if (threadIdx.x < 128) ts[threadIdx.x] = t1[threadIdx.x];
  __syncthreads();
  int i = blockIdx.x*256 + threadIdx.x;
  float di = dinv[i];
  int eo = off[i], n = cnt[i];
  float sx = di * x[i], s1 = di;       // self-loop terms
  int t = 0;
  for (; t + 4 <= n; t += 4){
    int a = csrc[eo+t], b = csrc[eo+t+1], c = csrc[eo+t+2], d = csrc[eo+t+3];
    float da = dinv[a], db = dinv[b], dc = dinv[c], dd = dinv[d];
    float xa = x[a], xb = x[b], xc = x[c], xd = x[d];
    sx += da*xa + db*xb + dc*xc + dd*xd;
    s1 += da + db + dc + dd;
  }
  for (; t < n; ++t){
    int s = csrc[eo + t]; float ds = dinv[s];
    sx += ds * x[s]; s1 += ds;
  }
  float a_ = di * sx, sr = di * s1;
  int sc = 0;
  for (int q = 0; q < 128; q++) sc += (ts[q] < a_) ? 1 : 0;
  recE[i] = make_float4(di, a_, __int_as_float(sc), __int_as_float(eo));
  recD[i] = make_float4(di, sr, 0.f, __int_as_float(eo));
}

// ---------------- fused encoder GCN2 + relu + mean-pool ----------------
__global__ void __launch_bounds__(256) k_enc_agg(
    const float4* __restrict__ recE, const int* __restrict__ cnt,
    const int* __restrict__ csrc, const float4* __restrict__ AC,
    const float* __restrict__ b2, float* __restrict__ hgsum)
{
  int bid  = blockIdx.x;               // 2048 blocks; g = bid&63 keeps a graph on one XCD
  int g    = bid & 63;
  int part = bid >> 6;                 // 0..31
  int lane = threadIdx.x & 31;
  int nrow = threadIdx.x >> 5;
  int base = g*NNPG + part*128;
  float4 bb = ((const float4*)b2)[lane];
  float gx = 0.f, gy = 0.f, gz = 0.f, gw = 0.f;
  for (int it = 0; it < 16; ++it){
    int i = base + it*8 + nrow;
    float4 r0 = recE[i];
    int eo = __float_as_int(r0.w);
    int n  = cnt[i];
    float di = r0.x;
    const float4* p = AC + ((size_t)__float_as_int(r0.z)*32 + lane)*2;
    float4 av = p[0], cv = p[1];
    float d2 = di*di, ca = r0.y*d2;
    float accx = ca*av.x + d2*cv.x;
    float accy = ca*av.y + d2*cv.y;
    float accz = ca*av.z + d2*cv.z;
    float accw = ca*av.w + d2*cv.w;
    int t = 0;
    for (; t + 4 <= n; t += 4){
      int sa = csrc[eo+t], sb = csrc[eo+t+1], sc_ = csrc[eo+t+2], sd = csrc[eo+t+3];
      float4 ra = recE[sa], rb = recE[sb], rc = recE[sc_], rd = recE[sd];
      const float4* qa = AC + ((size_t)__float_as_int(ra.z)*32 + lane)*2;
      const float4* qb = AC + ((size_t)__float_as_int(rb.z)*32 + lane)*2;
      const float4* qc = AC + ((size_t)__float_as_int(rc.z)*32 + lane)*2;
      const float4* qd = AC + ((size_t)__float_as_int(rd.z)*32 + lane)*2;
      float4 a1 = qa[0], c1 = qa[1];
      float4 a2 = qb[0], c2 = qb[1];
      float4 a3 = qc[0], c3 = qc[1];
      float4 a4 = qd[0], c4 = qd[1];
      float w1_ = ra.x*di, wa1 = w1_*ra.y;
      float w2_ = rb.x*di, wa2 = w2_*rb.y;
      float w3_ = rc.x*di, wa3 = w3_*rc.y;
      float w4_ = rd.x*di, wa4 = w4_*rd.y;
      accx = fmaf(wa1,a1.x,fmaf(w1_,c1.x,accx)); accy = fmaf(wa1,a1.y,fmaf(w1_,c1.y,accy));
      accz = fmaf(wa1,a1.z,fmaf(w1_,c1.z,accz)); accw = fmaf(wa1,a1.w,fmaf(w1_,c1.w,accw));
      accx = fmaf(wa2,a2.x,fmaf(w2_,c2.x,accx)); accy = fmaf(wa2,a2.y,fmaf(w2_,c2.y,accy));
      accz = fmaf(wa2,a2.z,fmaf(w2_,c2.z,accz)); accw = fmaf(wa2,a2.w,fmaf(w2_,c2.w,accw));
      accx = fmaf(wa3,a3.x,fmaf(w3_,c3.x,accx)); accy = fmaf(wa3,a3.y,fmaf(w3_,c3.y,accy));
      accz = fmaf(wa3,a3.z,fmaf(w3_,c3.z,accz)); accw = fmaf(wa3,a3.w,fmaf(w3_,c3.w,accw));
      accx = fmaf(wa4,a4.x,fmaf(w4_,c4.x,accx)); accy = fmaf(wa4,a4.y,fmaf(w4_,c4.y,accy));
      accz = fmaf(wa4,a4.z,fmaf(w4_,c4.z,accz)); accw = fmaf(wa4,a4.w,fmaf(w4_,c4.w,accw));
    }
    for (; t < n; ++t){
      int src = csrc[eo + t];
      float4 rs = recE[src];
      const float4* q = AC + ((size_t)__float_as_int(rs.z)*32 + lane)*2;
      float4 a1 = q[0], c1 = q[1];
      float wg = rs.x*di, wa = wg*rs.y;
      accx = fmaf(wa,a1.x,fmaf(wg,c1.x,accx)); accy = fmaf(wa,a1.y,fmaf(wg,c1.y,accy));
      accz = fmaf(wa,a1.z,fmaf(wg,c1.z,accz)); accw = fmaf(wa,a1.w,fmaf(wg,c1.w,accw));
    }
    gx += fmaxf(accx + bb.x, 0.f);
    gy += fmaxf(accy + bb.y, 0.f);
    gz += fmaxf(accz + bb.z, 0.f);
    gw += fmaxf(accw + bb.w, 0.f);
  }
  __shared__ float red[256*4];
  red[threadIdx.x*4+0] = gx; red[threadIdx.x*4+1] = gy;
  red[threadIdx.x*4+2] = gz; red[threadIdx.x*4+3] = gw;
  __syncthreads();
  if (nrow == 0){
    float tx=0.f, ty=0.f, tz=0.f, tw=0.f;
    for (int r2 = 0; r2 < 8; r2++){
      int t2 = (r2*32 + lane)*4;
      tx += red[t2]; ty += red[t2+1]; tz += red[t2+2]; tw += red[t2+3];
    }
    atomicAdd(&hgsum[g*HD + lane*4 + 0], tx);
    atomicAdd(&hgsum[g*HD + lane*4 + 1], ty);
    atomicAdd(&hgsum[g*HD + lane*4 + 2], tz);
    atomicAdd(&hgsum[g*HD + lane*4 + 3], tw);
  }
}

// ------- per-graph dense chain + decoder table (fused, 1 block/graph) -------
__global__ void __launch_bounds__(128) k_small_tab2(
    const float* __restrict__ hgsum,
    const float* __restrict__ mu_w, const float* __restrict__ mu_b,
    const float* __restrict__ lv_w, const float* __restrict__ lv_b,
    const float* __restrict__ eps,
    const float* __restrict__ zn_w, const float* __restrict__ zn_b,
    const float* __restrict__ dec_w1, const float* __restrict__ dec_b1,
    const float* __restrict__ dec_w2,
    float* __restrict__ out_mu, float* __restrict__ out_lv, float* __restrict__ out_z,
    float* __restrict__ t2, float* __restrict__ AC2)
{
  int g = blockIdx.x, tid = threadIdx.x;
  __shared__ float hg[128], zsh[64], znsh[128], ush[128];
  __shared__ float ts[128], bs[128];
  __shared__ int ks[128], jr[128];
  hg[tid] = hgsum[g*HD + tid] * (1.0f/4096.0f);
  __syncthreads();
  if (tid < 64){
    int l = tid;
    float m = mu_b[l], v = lv_b[l];
    for (int k = 0; k < HD; k++){
      float hv = hg[k];
      m = fmaf(hv, mu_w[k*LD + l], m);
      v = fmaf(hv, lv_w[k*LD + l], v);
    }
    int o = g*LD + l;
    out_mu[o] = m; out_lv[o] = v;
    float zv = fmaf(expf(0.5f*v), eps[o], m);
    out_z[o] = zv; zsh[l] = zv;
  }
  __syncthreads();
  { // zn
    int k = tid;
    float acc = zn_b[k];
    for (int l = 0; l < LD; l++) acc = fmaf(zsh[l], zn_w[l*HD + k], acc);
    znsh[k] = acc;
  }
  __syncthreads();
  { // u = zn @ dec_w1
    int k = tid;
    float acc = 0.f;
    for (int j = 0; j < HD; j++) acc = fmaf(znsh[j], dec_w1[j*HD + k], acc);
    ush[k] = acc;
  }
  __syncthreads();
  // ---- decoder table (same incremental scheme as k_tab1, w := ush) ----
  int j = tid;
  float w = ush[j], b = dec_b1[j];
  float t; int kind;
  if (w != 0.0f){ t = -b / w; kind = (w > 0.0f) ? 0 : 1; }
  else          { t = INFINITY; kind = 2; }
  ts[j] = t; ks[j] = kind; bs[j] = b; jr[j] = -1;
  __syncthreads();
  int r = 0;
  for (int q = 0; q < 128; q++){
    if (ks[q] != 2){
      float tq = ts[q];
      if (tq < t || (tq == t && q < j)) r++;
    }
  }
  t2[g*HD + j] = t;
  if (kind != 2) jr[r] = j;
  __syncthreads();
  int k = j;
  float a = 0.f, c = 0.f;
  for (int q = 0; q < 128; q++){
    int kd = ks[q];
    bool act = (kd == 1) || (kd == 2 && bs[q] > 0.0f);
    if (act){ float v = dec_w2[q*HD + k]; a = fmaf(ush[q], v, a); c = fmaf(bs[q], v, c); }
  }
  float* ACg = AC2 + (size_t)g*NSEG*256;
  int base = (k>>2)*8 + (k&3);
  ACg[base] = a; ACg[base+4] = c;
  for (int s = 0; s < 128; s++){
    int q = jr[s];
    if (q >= 0){
      float sg = (ks[q] == 0) ? 1.f : -1.f;
      float v  = dec_w2[q*HD + k];
      a = fmaf(sg*ush[q], v, a);
      c = fmaf(sg*bs[q], v, c);
    }
    int o = (s+1)*256 + base;
    ACg[o] = a; ACg[o+4] = c;
  }
}

__global__ void k_seg2(const float* __restrict__ t2, float4* __restrict__ recD){
  __shared__ float ts[128];
  int i = blockIdx.x*256 + threadIdx.x;
  int g = i >> 12;
  if (threadIdx.x < 128) ts[threadIdx.x] = t2[g*HD + threadIdx.x];
  __syncthreads();
  float a = recD[i].y;
  int sc = 0;
  for (int q = 0; q < 128; q++) sc += (ts[q] < a) ? 1 : 0;
  ((float*)recD)[i*4 + 2] = __int_as_float(sc);
}

// ---------------- fused decoder GCN2 + relu + out-proj + tanh ----------------
__global__ void __launch_bounds__(256) k_dec_agg(
    const float4* __restrict__ recD, const int* __restrict__ cnt,
    const int* __restrict__ csrc, const float4* __restrict__ AC2,
    const float* __restrict__ b2, const float* __restrict__ ow, const float* __restrict__ ob,
    float* __restrict__ recon)
{
  int bid  = blockIdx.x;
  int g    = bid & 63;
  int part = bid >> 6;
  int lane = threadIdx.x & 31;
  int nrow = threadIdx.x >> 5;
  int base = g*NNPG + part*128;
  const float4* AC = AC2 + (size_t)g*NSEG*64;
  float4 bb  = ((const float4*)b2)[lane];
  float4 owv = ((const float4*)ow)[lane];
  float obv = ob[0];
  for (int it = 0; it < 16; ++it){
    int i = base + it*8 + nrow;
    float4 r0 = recD[i];
    int eo = __float_as_int(r0.w);
    int n  = cnt[i];
    float di = r0.x;
    const float4* p = AC + ((size_t)__float_as_int(r0.z)*32 + lane)*2;
    float4 av = p[0], cv = p[1];
    float d2 = di*di, ca = r0.y*d2;
    float accx = ca*av.x + d2*cv.x;
    float accy = ca*av.y + d2*cv.y;
    float accz = ca*av.z + d2*cv.z;
    float accw = ca*av.w + d2*cv.w;
    int t = 0;
    for (; t + 4 <= n; t += 4){
      int sa = csrc[eo+t], sb = csrc[eo+t+1], sc_ = csrc[eo+t+2], sd = csrc[eo+t+3];
      float4 ra = recD[sa], rb = recD[sb], rc = recD[sc_], rd = recD[sd];
      const float4* qa = AC + ((size_t)__float_as_int(ra.z)*32 + lane)*2;
      const float4* qb = AC + ((size_t)__float_as_int(rb.z)*32 + lane)*2;
      const float4* qc = AC + ((size_t)__float_as_int(rc.z)*32 + lane)*2;
      const float4* qd = AC + ((size_t)__float_as_int(rd.z)*32 + lane)*2;
      float4 a1 = qa[0], c1 = qa[1];
      float4 a2 = qb[0], c2 = qb[1];
      float4 a3 = qc[0], c3 = qc[1];
      float4 a4 = qd[0], c4 = qd[1];
      float w1_ = ra.x*di, wa1 = w1_*ra.y;
      float w2_ = rb.x*di, wa2 = w2_*rb.y;
      float w3_ = rc.x*di, wa3 = w3_*rc.y;
      float w4_ = rd.x*di, wa4 = w4_*rd.y;
      accx = fmaf(wa1,a1.x,fmaf(w1_,c1.x,accx)); accy = fmaf(wa1,a1.y,fmaf(w1_,c1.y,accy));
      accz = fmaf(wa1,a1.z,fmaf(w1_,c1.z,accz)); accw = fmaf(wa1,a1.w,fmaf(w1_,c1.w,accw));
      accx = fmaf(wa2,a2.x,fmaf(w2_,c2.x,accx)); accy = fmaf(wa2,a2.y,fmaf(w2_,c2.y,accy));
      accz = fmaf(wa2,a2.z,fmaf(w2_,c2.z,accz)); accw = fmaf(wa2,a2.w,fmaf(w2_,c2.w,accw));
      accx = fmaf(wa3,a3.x,fmaf(w3_,c3.x,accx)); accy = fmaf(wa3,a3.y,fmaf(w3_,c3.y,accy));
      accz = fmaf(wa3,a3.z,fmaf(w3_,c3.z,accz)); accw = fmaf(wa3,a3.w,fmaf(w3_,c3.w,accw));
      accx = fmaf(wa4,a4.x,fmaf(w4_,c4.x,accx)); accy = fmaf(wa4,a4.y,fmaf(w4_,c4.y,accy));
      accz = fmaf(wa4,a4.z,fmaf(w4_,c4.z,accz)); accw = fmaf(wa4,a4.w,fmaf(w4_,c4.w,accw));
    }
    for (; t < n; ++t){
      int src = csrc[eo + t];
      float4 rs = recD[src];
      const float4* q = AC + ((size_t)__float_as_int(rs.z)*32 + lane)*2;
      float4 a1 = q[0], c1 = q[1];
      float wg = rs.x*di, wa = wg*rs.y;
      accx = fmaf(wa,a1.x,fmaf(wg,c1.x,accx)); accy = fmaf(wa,a1.y,fmaf(wg,c1.y,accy));
      accz = fmaf(wa,a1.z,fmaf(wg,c1.z,accz)); accw = fmaf(wa,a1.w,fmaf(wg,c1.w,accw));
    }
    float hx = fmaxf(accx + bb.x, 0.f);
    float hy = fmaxf(accy + bb.y, 0.f);
    float hz = fmaxf(accz + bb.z, 0.f);
    float hw = fmaxf(accw + bb.w, 0.f);
    float dsum = hx*owv.x + hy*owv.y + hz*owv.z + hw*owv.w;
    for (int o2 = 16; o2 > 0; o2 >>= 1) dsum += __shfl_down(dsum, o2, 32);
    if (lane == 0) recon[i] = tanhf(dsum + obv);
  }
}

// ---------------- launch ----------------
extern "C" void kernel_launch(void* const* d_in, const int* in_sizes, int n_in,
                              void* d_out, int out_size, void* d_ws, size_t ws_size,
                              hipStream_t stream){
  (void)in_sizes; (void)n_in; (void)out_size; (void)ws_size;
  const float* x      = (const float*)d_in[0];
  const float* eps    = (const float*)d_in[1];
  const float* enc_w1 = (const float*)d_in[2];
  const float* enc_b1 = (const float*)d_in[3];
  const float* enc_w2 = (const float*)d_in[4];
  const float* enc_b2 = (const float*)d_in[5];
  const float* mu_w   = (const float*)d_in[6];
  const float* mu_b   = (const float*)d_in[7];
  const float* lv_w   = (const float*)d_in[8];
  const float* lv_b   = (const float*)d_in[9];
  const float* zn_w   = (const float*)d_in[10];
  const float* zn_b   = (const float*)d_in[11];
  const float* dec_w1 = (const float*)d_in[12];
  const float* dec_b1 = (const float*)d_in[13];
  const float* dec_w2 = (const float*)d_in[14];
  const float* dec_b2 = (const float*)d_in[15];
  const float* out_w  = (const float*)d_in[16];
  const float* out_b  = (const float*)d_in[17];
  const int*   ei     = (const int*)d_in[18];

  float* out       = (float*)d_out;
  float* out_recon = out;
  float* out_mu    = out + NTOT;
  float* out_lv    = out_mu + BG*LD;
  float* out_z     = out_lv + BG*LD;

  char* w = (char*)d_ws;
  size_t off_b = 0;
  auto alloc = [&](size_t bytes)->void*{
    void* p = w + off_b;
    off_b += (bytes + 255) & ~(size_t)255;
    return p;
  };
  int*    cnt    = (int*)   alloc((size_t)NTOT*4);
  int*    csroff = (int*)   alloc((size_t)NTOT*4);
  int*    cursor = (int*)   alloc((size_t)NTOT*4);
  int*    csrc   = (int*)   alloc((size_t)ET*4);
  int*    bsum   = (int*)   alloc(1024*4);
  float*  dinv   = (float*) alloc((size_t)NTOT*4);
  float4* recE   = (float4*)alloc((size_t)NTOT*16);
  float4* recD   = (float4*)alloc((size_t)NTOT*16);
  float*  t1     = (float*) alloc(128*4);
  float*  AC1    = (float*) alloc((size_t)NSEG*256*4);
  float*  hgsum  = (float*) alloc((size_t)BG*HD*4);
  float*  t2     = (float*) alloc((size_t)BG*HD*4);
  float*  AC2    = (float*) alloc((size_t)BG*NSEG*256*4);

  hipMemsetAsync(cnt,   0, (size_t)NTOT*4, stream);
  hipMemsetAsync(hgsum, 0, (size_t)BG*HD*4, stream);

  k_count<<<ET/256, 256, 0, stream>>>(ei, cnt);
  k_scan1<<<NTOT/256, 256, 0, stream>>>(cnt, csroff, bsum, dinv);
  k_scan2<<<1, 1024, 0, stream>>>(bsum);
  k_scan3<<<NTOT/256, 256, 0, stream>>>(csroff, bsum, cursor);
  k_place<<<ET/256, 256, 0, stream>>>(ei, cursor, csrc);

  k_tab1<<<1, 128, 0, stream>>>(enc_w1, enc_b1, enc_w2, t1, AC1);
  k_ax  <<<NTOT/256, 256, 0, stream>>>(x, dinv, csroff, cnt, csrc, t1, recE, recD);

  k_enc_agg<<<2048, 256, 0, stream>>>(recE, cnt, csrc, (const float4*)AC1, enc_b2, hgsum);

  k_small_tab2<<<BG, 128, 0, stream>>>(hgsum, mu_w, mu_b, lv_w, lv_b, eps,
                                       zn_w, zn_b, dec_w1, dec_b1, dec_w2,
                                       out_mu, out_lv, out_z, t2, AC2);

  k_seg2<<<NTOT/256, 256, 0, stream>>>(t2, recD);

  k_dec_agg<<<2048, 256, 0, stream>>>(recD, cnt, csrc, (const float4*)AC2,
                                      dec_b2, out_w, out_b, out_recon);
}